// Round 1
// baseline (288.683 us; speedup 1.0000x reference)
//
#include <hip/hip_runtime.h>

#define N 128
#define NN (N * N)          // 16384
#define M 2048

// ---------------------------------------------------------------------------
// Prep: evc0, evc1 (Gram-Schmidt), softplus+normalized eigenvalues.
// sqrt(lam_p) is FOLDED into the stored eigenvectors so the main kernel
// computes v = s0' - s1' with no lam multiplies.
// ws layout: [0..128) e0r' | [128..256) e0i' | [256..384) e1r' | [384..512) e1i'
// ---------------------------------------------------------------------------
__device__ __forceinline__ float block_reduce128(float v, float* red, int i) {
    __syncthreads();
    red[i] = v;
    __syncthreads();
    for (int off = 64; off > 0; off >>= 1) {
        if (i < off) red[i] += red[i + off];
        __syncthreads();
    }
    return red[0];
}

__global__ void prep_kernel(const float* __restrict__ theta,
                            const float* __restrict__ evl,
                            float* __restrict__ ws) {
    __shared__ float red[N];
    const int i = threadIdx.x;   // 128 threads

    float c0r = theta[i], c0i = theta[N + i];
    float s0 = block_reduce128(c0r * c0r + c0i * c0i, red, i);
    float inv0 = rsqrtf(s0);
    float a0r = c0r * inv0, a0i = c0i * inv0;

    // c1 -= vdot(evc0, c1) * evc0   (vdot conjugates first arg)
    float c1r = theta[2 * N + i], c1i = theta[3 * N + i];
    float dr = block_reduce128(a0r * c1r + a0i * c1i, red, i);
    float di = block_reduce128(a0r * c1i - a0i * c1r, red, i);
    c1r -= dr * a0r - di * a0i;
    c1i -= dr * a0i + di * a0r;

    float s1 = block_reduce128(c1r * c1r + c1i * c1i, red, i);
    float inv1 = rsqrtf(s1);

    float l0 = log1pf(expf(evl[0]));   // softplus
    float l1 = log1pf(expf(evl[1]));
    float inl = rsqrtf(l0 * l0 + l1 * l1);
    float sc0 = sqrtf(l0 * inl);       // sqrt(lam0)
    float sc1 = sqrtf(l1 * inl);       // sqrt(lam1)

    ws[i]         = a0r * sc0;
    ws[N + i]     = a0i * sc0;
    ws[2 * N + i] = c1r * inv1 * sc1;
    ws[3 * N + i] = c1i * inv1 * sc1;
}

// ---------------------------------------------------------------------------
// Main: one block per basis operator k.
// v_k = sum_p (+/-) sum_i e_p'[i] * conj( (B_k e_p')[i] )
// Per chunk (one float4 of row i): acc_p = sum_j conj(B[i,j]) * conj(e_p'[j]),
// then v_p += e_p'[i] * acc_p.  j4 = t&31 is loop-invariant -> E vectors
// hoisted to registers (no per-chunk ds_read_b128).
// Depth-3 software pipeline on the global stream (A0..A2 / B0..B2).
// ---------------------------------------------------------------------------
#define ELEM(comp, A, B)                                         \
    {                                                            \
        a0r = fmaf((A).comp, E0r.comp, a0r);                     \
        a0r = fmaf(-(B).comp, E0i.comp, a0r);                    \
        a0i = fmaf(-(A).comp, E0i.comp, a0i);                    \
        a0i = fmaf(-(B).comp, E0r.comp, a0i);                    \
        a1r = fmaf((A).comp, E1r.comp, a1r);                     \
        a1r = fmaf(-(B).comp, E1i.comp, a1r);                    \
        a1i = fmaf(-(A).comp, E1i.comp, a1i);                    \
        a1i = fmaf(-(B).comp, E1r.comp, a1i);                    \
    }

#define STEP(c, A, B)                                            \
    {                                                            \
        float a0r = 0.f, a0i = 0.f, a1r = 0.f, a1i = 0.f;        \
        ELEM(x, A, B) ELEM(y, A, B) ELEM(z, A, B) ELEM(w, A, B)  \
        const int irow = bi0 + 8 * (c);                          \
        const float er0 = le[irow],       ei0 = le[128 + irow];  \
        const float er1 = le[256 + irow], ei1 = le[384 + irow];  \
        v0r = fmaf(er0, a0r, v0r); v0r = fmaf(-ei0, a0i, v0r);   \
        v0i = fmaf(er0, a0i, v0i); v0i = fmaf(ei0, a0r, v0i);    \
        v1r = fmaf(er1, a1r, v1r); v1r = fmaf(-ei1, a1i, v1r);   \
        v1i = fmaf(er1, a1i, v1i); v1i = fmaf(ei1, a1r, v1i);    \
    }

#define PF(A, B, c)                                              \
    {                                                            \
        A = brk[t + 256 * (c)];                                  \
        B = bik[t + 256 * (c)];                                  \
    }

__global__ __launch_bounds__(256, 8) void main_kernel(
        const float4* __restrict__ br, const float4* __restrict__ bi,
        const float* __restrict__ ws, float* __restrict__ partial) {
    __shared__ __align__(16) float le[4 * N];   // e0r' | e0i' | e1r' | e1i'
    __shared__ float swr[4], swi[4];
    const int t = threadIdx.x;
    const int k = blockIdx.x;

    const float4* brk = br + (size_t)k * (NN / 4);
    const float4* bik = bi + (size_t)k * (NN / 4);

    // issue first 3 chunks of both streams (6 loads in flight)
    float4 A0 = brk[t],       B0 = bik[t];
    float4 A1 = brk[t + 256], B1 = bik[t + 256];
    float4 A2 = brk[t + 512], B2 = bik[t + 512];

    if (t < 128) ((float4*)le)[t] = ((const float4*)ws)[t];
    __syncthreads();

    const int j4  = t & 31;    // float4 column index, chunk-invariant
    const int bi0 = t >> 5;    // base row, i = bi0 + 8*c
    const float4* e4 = (const float4*)le;
    const float4 E0r = e4[j4],      E0i = e4[32 + j4];
    const float4 E1r = e4[64 + j4], E1i = e4[96 + j4];

    float v0r = 0.f, v0i = 0.f, v1r = 0.f, v1i = 0.f;

    STEP(0,  A0, B0) PF(A0, B0, 3)
    STEP(1,  A1, B1) PF(A1, B1, 4)
    STEP(2,  A2, B2) PF(A2, B2, 5)
    STEP(3,  A0, B0) PF(A0, B0, 6)
    STEP(4,  A1, B1) PF(A1, B1, 7)
    STEP(5,  A2, B2) PF(A2, B2, 8)
    STEP(6,  A0, B0) PF(A0, B0, 9)
    STEP(7,  A1, B1) PF(A1, B1, 10)
    STEP(8,  A2, B2) PF(A2, B2, 11)
    STEP(9,  A0, B0) PF(A0, B0, 12)
    STEP(10, A1, B1) PF(A1, B1, 13)
    STEP(11, A2, B2) PF(A2, B2, 14)
    STEP(12, A0, B0) PF(A0, B0, 15)
    STEP(13, A1, B1)
    STEP(14, A2, B2)
    STEP(15, A0, B0)

    float vr = v0r - v1r;
    float vi = v0i - v1i;

    // wave-64 reduce, then cross-wave via LDS
    for (int off = 32; off > 0; off >>= 1) {
        vr += __shfl_down(vr, off);
        vi += __shfl_down(vi, off);
    }
    const int wave = t >> 6, lane = t & 63;
    if (lane == 0) { swr[wave] = vr; swi[wave] = vi; }
    __syncthreads();
    if (t == 0) {
        float R = swr[0] + swr[1] + swr[2] + swr[3];
        float I = swi[0] + swi[1] + swi[2] + swi[3];
        partial[k] = R * R + I * I;   // no atomics: per-block partial
    }
}

// ---------------------------------------------------------------------------
// Final sum of the 2048 per-block partials (replaces memset + atomicAdd tail).
// ---------------------------------------------------------------------------
__global__ __launch_bounds__(256) void reduce_kernel(
        const float* __restrict__ partial, float* __restrict__ out) {
    __shared__ float sw[4];
    const int t = threadIdx.x;
    float s = 0.f;
    #pragma unroll
    for (int r = 0; r < M / 256; ++r) s += partial[t + 256 * r];
    for (int off = 32; off > 0; off >>= 1) s += __shfl_down(s, off);
    if ((t & 63) == 0) sw[t >> 6] = s;
    __syncthreads();
    if (t == 0) out[0] = sw[0] + sw[1] + sw[2] + sw[3];
}

extern "C" void kernel_launch(void* const* d_in, const int* in_sizes, int n_in,
                              void* d_out, int out_size, void* d_ws, size_t ws_size,
                              hipStream_t stream) {
    const float* basis_re = (const float*)d_in[0];
    const float* basis_im = (const float*)d_in[1];
    const float* theta    = (const float*)d_in[2];
    const float* evl      = (const float*)d_in[3];
    float* out = (float*)d_out;
    float* ws  = (float*)d_ws;   // [0..512) prep vectors | [512..2560) partials

    prep_kernel<<<1, 128, 0, stream>>>(theta, evl, ws);
    main_kernel<<<M, 256, 0, stream>>>((const float4*)basis_re,
                                       (const float4*)basis_im,
                                       ws, ws + 512);
    reduce_kernel<<<1, 256, 0, stream>>>(ws + 512, out);
}

// Round 2
// 274.673 us; speedup vs baseline: 1.0510x; 1.0510x over previous
//
#include <hip/hip_runtime.h>

#define N 128
#define NN (N * N)          // 16384
#define M 2048

typedef float fvec4 __attribute__((ext_vector_type(4)));

// ---------------------------------------------------------------------------
// Prep: evc0, evc1 (Gram-Schmidt), softplus+normalized eigenvalues.
// sqrt(lam_p) folded into the stored eigenvectors.
// ws layout: [0..128) e0r' | [128..256) e0i' | [256..384) e1r' | [384..512) e1i'
// ---------------------------------------------------------------------------
__device__ __forceinline__ float block_reduce128(float v, float* red, int i) {
    __syncthreads();
    red[i] = v;
    __syncthreads();
    for (int off = 64; off > 0; off >>= 1) {
        if (i < off) red[i] += red[i + off];
        __syncthreads();
    }
    return red[0];
}

__global__ void prep_kernel(const float* __restrict__ theta,
                            const float* __restrict__ evl,
                            float* __restrict__ ws) {
    __shared__ float red[N];
    const int i = threadIdx.x;   // 128 threads

    float c0r = theta[i], c0i = theta[N + i];
    float s0 = block_reduce128(c0r * c0r + c0i * c0i, red, i);
    float inv0 = rsqrtf(s0);
    float a0r = c0r * inv0, a0i = c0i * inv0;

    float c1r = theta[2 * N + i], c1i = theta[3 * N + i];
    float dr = block_reduce128(a0r * c1r + a0i * c1i, red, i);
    float di = block_reduce128(a0r * c1i - a0i * c1r, red, i);
    c1r -= dr * a0r - di * a0i;
    c1i -= dr * a0i + di * a0r;

    float s1 = block_reduce128(c1r * c1r + c1i * c1i, red, i);
    float inv1 = rsqrtf(s1);

    float l0 = log1pf(expf(evl[0]));   // softplus
    float l1 = log1pf(expf(evl[1]));
    float inl = rsqrtf(l0 * l0 + l1 * l1);
    float sc0 = sqrtf(l0 * inl);       // sqrt(lam0)
    float sc1 = sqrtf(l1 * inl);       // sqrt(lam1)

    ws[i]         = a0r * sc0;
    ws[N + i]     = a0i * sc0;
    ws[2 * N + i] = c1r * inv1 * sc1;
    ws[3 * N + i] = c1i * inv1 * sc1;
}

// ---------------------------------------------------------------------------
// Main: one block per basis operator k.
// Cache partitioning: br loaded NORMALLY (stays L3-resident, 128 MiB < 256 MiB),
// bi loaded NON-TEMPORALLY (streams from HBM, does not evict br).
// Depth-3 software pipeline pinned with sched_barrier(0) fences.
// ---------------------------------------------------------------------------
#define ELEM(comp, A, B)                                         \
    {                                                            \
        a0r = fmaf((A).comp, E0r.comp, a0r);                     \
        a0r = fmaf(-(B).comp, E0i.comp, a0r);                    \
        a0i = fmaf(-(A).comp, E0i.comp, a0i);                    \
        a0i = fmaf(-(B).comp, E0r.comp, a0i);                    \
        a1r = fmaf((A).comp, E1r.comp, a1r);                     \
        a1r = fmaf(-(B).comp, E1i.comp, a1r);                    \
        a1i = fmaf(-(A).comp, E1i.comp, a1i);                    \
        a1i = fmaf(-(B).comp, E1r.comp, a1i);                    \
    }

#define STEP(c, A, B)                                            \
    {                                                            \
        float a0r = 0.f, a0i = 0.f, a1r = 0.f, a1i = 0.f;        \
        ELEM(x, A, B) ELEM(y, A, B) ELEM(z, A, B) ELEM(w, A, B)  \
        const int irow = bi0 + 8 * (c);                          \
        const float er0 = le[irow],       ei0 = le[128 + irow];  \
        const float er1 = le[256 + irow], ei1 = le[384 + irow];  \
        v0r = fmaf(er0, a0r, v0r); v0r = fmaf(-ei0, a0i, v0r);   \
        v0i = fmaf(er0, a0i, v0i); v0i = fmaf(ei0, a0r, v0i);    \
        v1r = fmaf(er1, a1r, v1r); v1r = fmaf(-ei1, a1i, v1r);   \
        v1i = fmaf(er1, a1i, v1i); v1i = fmaf(ei1, a1r, v1i);    \
    }

// br: normal load (L3-resident). bi: non-temporal (stream, no-allocate).
#define PF(A, B, c)                                              \
    {                                                            \
        A = brk[t + 256 * (c)];                                  \
        B = __builtin_nontemporal_load(&bik[t + 256 * (c)]);     \
    }                                                            \
    __builtin_amdgcn_sched_barrier(0);

__global__ __launch_bounds__(256, 8) void main_kernel(
        const fvec4* __restrict__ br, const fvec4* __restrict__ bi,
        const float* __restrict__ ws, float* __restrict__ partial) {
    __shared__ __align__(16) float le[4 * N];   // e0r' | e0i' | e1r' | e1i'
    __shared__ float swr[4], swi[4];
    const int t = threadIdx.x;
    const int k = blockIdx.x;

    const fvec4* brk = br + (size_t)k * (NN / 4);
    const fvec4* bik = bi + (size_t)k * (NN / 4);

    // prologue: 3 chunks of both streams in flight (6 loads)
    fvec4 A0, B0, A1, B1, A2, B2;
    PF(A0, B0, 0)
    PF(A1, B1, 1)
    PF(A2, B2, 2)

    if (t < 128) ((fvec4*)le)[t] = ((const fvec4*)ws)[t];
    __syncthreads();

    const int j4  = t & 31;    // float4 column index, chunk-invariant
    const int bi0 = t >> 5;    // base row, i = bi0 + 8*c
    const fvec4* e4 = (const fvec4*)le;
    const fvec4 E0r = e4[j4],      E0i = e4[32 + j4];
    const fvec4 E1r = e4[64 + j4], E1i = e4[96 + j4];
    __builtin_amdgcn_sched_barrier(0);

    float v0r = 0.f, v0i = 0.f, v1r = 0.f, v1i = 0.f;

    STEP(0,  A0, B0) PF(A0, B0, 3)
    STEP(1,  A1, B1) PF(A1, B1, 4)
    STEP(2,  A2, B2) PF(A2, B2, 5)
    STEP(3,  A0, B0) PF(A0, B0, 6)
    STEP(4,  A1, B1) PF(A1, B1, 7)
    STEP(5,  A2, B2) PF(A2, B2, 8)
    STEP(6,  A0, B0) PF(A0, B0, 9)
    STEP(7,  A1, B1) PF(A1, B1, 10)
    STEP(8,  A2, B2) PF(A2, B2, 11)
    STEP(9,  A0, B0) PF(A0, B0, 12)
    STEP(10, A1, B1) PF(A1, B1, 13)
    STEP(11, A2, B2) PF(A2, B2, 14)
    STEP(12, A0, B0) PF(A0, B0, 15)
    STEP(13, A1, B1)
    STEP(14, A2, B2)
    STEP(15, A0, B0)

    float vr = v0r - v1r;
    float vi = v0i - v1i;

    // wave-64 reduce, then cross-wave via LDS
    for (int off = 32; off > 0; off >>= 1) {
        vr += __shfl_down(vr, off);
        vi += __shfl_down(vi, off);
    }
    const int wave = t >> 6, lane = t & 63;
    if (lane == 0) { swr[wave] = vr; swi[wave] = vi; }
    __syncthreads();
    if (t == 0) {
        float R = swr[0] + swr[1] + swr[2] + swr[3];
        float I = swi[0] + swi[1] + swi[2] + swi[3];
        partial[k] = R * R + I * I;
    }
}

// ---------------------------------------------------------------------------
// Final sum of the 2048 per-block partials.
// ---------------------------------------------------------------------------
__global__ __launch_bounds__(256) void reduce_kernel(
        const float* __restrict__ partial, float* __restrict__ out) {
    __shared__ float sw[4];
    const int t = threadIdx.x;
    float s = 0.f;
    #pragma unroll
    for (int r = 0; r < M / 256; ++r) s += partial[t + 256 * r];
    for (int off = 32; off > 0; off >>= 1) s += __shfl_down(s, off);
    if ((t & 63) == 0) sw[t >> 6] = s;
    __syncthreads();
    if (t == 0) out[0] = sw[0] + sw[1] + sw[2] + sw[3];
}

extern "C" void kernel_launch(void* const* d_in, const int* in_sizes, int n_in,
                              void* d_out, int out_size, void* d_ws, size_t ws_size,
                              hipStream_t stream) {
    const float* basis_re = (const float*)d_in[0];
    const float* basis_im = (const float*)d_in[1];
    const float* theta    = (const float*)d_in[2];
    const float* evl      = (const float*)d_in[3];
    float* out = (float*)d_out;
    float* ws  = (float*)d_ws;   // [0..512) prep vectors | [512..2560) partials

    prep_kernel<<<1, 128, 0, stream>>>(theta, evl, ws);
    main_kernel<<<M, 256, 0, stream>>>((const fvec4*)basis_re,
                                       (const fvec4*)basis_im,
                                       ws, ws + 512);
    reduce_kernel<<<1, 256, 0, stream>>>(ws + 512, out);
}